// Round 9
// baseline (168.795 us; speedup 1.0000x reference)
//
#include <hip/hip_runtime.h>
#include <math.h>

#define Bv 4
#define Nv 256
#define Cv 32
#define Mv 4
#define OUTv 64
#define MCv (Mv*Cv)      // 128

typedef _Float16 h8 __attribute__((ext_vector_type(8)));
typedef _Float16 h4 __attribute__((ext_vector_type(4)));
typedef float f4 __attribute__((ext_vector_type(4)));

// ---- static device scratch ----
__device__ __align__(16) float g_cs  [Bv * Nv * Cv];
__device__ __align__(16) float g_dgx [Bv * Nv * Cv];
__device__ __align__(16) float g_nb  [Bv * Nv * Mv];
__device__ __align__(16) float g_rwP [Bv * 64 * Nv * Mv];   // rs@w1 partials, 1 MB
__device__ __align__(16) float g_rcs2R[8 * Bv * MCv];   // 8 XCD-aligned atomic replicas
__device__ __align__(16) float g_ds2R [8 * Bv * MCv];   // 8 XCD-aligned atomic replicas
__device__ __align__(16) float g_addv[Bv * Nv * OUTv];  // addv WITHOUT the w0d (t0) term
__device__ __align__(16) _Float16 g_wfrag[8 * 4 * 64 * 8];   // 32 KB

// ---------------- K1: single coalesced sweep of x --------------------------
// Block bx<64 owns rows i0=4bx..+3: streams them once, producing
//   cs[i,c]   (row sums, direct)
//   dgx[i,c]  (diag copy)
//   rwP[bx][j][m] = sum_{i in rows} sum_c x[i,j,c] * w1[c*4+m]   (rs pre-contract)
// Blocks bx in [64,72]: pack w2d / zero replicas (b==0 only).
__global__ __launch_bounds__(256) void k_contract1(const float* __restrict__ x,
                                                   const float* __restrict__ w2d,
                                                   const float* __restrict__ w1) {
    int bx = blockIdx.x, b = blockIdx.y;
    int t = threadIdx.x;
    if (bx >= 64) {
        if (b != 0) return;
        int r = bx - 64;
        if (r == 8) {                    // zero rcs2/ds2 replicas (2 x 4096 floats)
            float4 z = {0.f,0.f,0.f,0.f};
            #pragma unroll
            for (int k = 0; k < 4; k++) {
                ((float4*)g_rcs2R)[k * 256 + t] = z;
                ((float4*)g_ds2R )[k * 256 + t] = z;
            }
            return;
        }
        int fi = r * 256 + t;
        int s = fi >> 8, q = (fi >> 6) & 3, lane = fi & 63;
        int k0 = s * 32 + ((lane >> 4) << 3);
        int o = q * 16 + (lane & 15);
        #pragma unroll
        for (int jj = 0; jj < 8; jj++)
            g_wfrag[fi * 8 + jj] = (_Float16)w2d[(size_t)(k0 + jj) * OUTv + o];
        return;
    }
    int c4 = t & 7, jb = t >> 3;            // 32 j-bases x 8 c4
    int i0 = bx * 4;
    const float4* xb4 = (const float4*)(x + (size_t)b * Nv * Nv * Cv);
    __shared__ __align__(16) float4 red2[32][8];
    __shared__ float redw[256][36];         // 36 KB, padded stride

    float4 acc8[8];
    #pragma unroll
    for (int k = 0; k < 8; k++) acc8[k] = {0.f,0.f,0.f,0.f};

    for (int r = 0; r < 4; r++) {
        int i = i0 + r;
        float4 v[8];
        #pragma unroll
        for (int k = 0; k < 8; k++)
            v[k] = xb4[((size_t)i * Nv + jb + 32 * k) * 8 + c4];
        float4 rsum = {0.f,0.f,0.f,0.f};
        #pragma unroll
        for (int k = 0; k < 8; k++) {
            acc8[k].x += v[k].x; acc8[k].y += v[k].y;
            acc8[k].z += v[k].z; acc8[k].w += v[k].w;
            rsum.x += v[k].x; rsum.y += v[k].y;
            rsum.z += v[k].z; rsum.w += v[k].w;
        }
        red2[jb][c4] = rsum;
        __syncthreads();
        if (t < 8) {
            float4 s = {0.f,0.f,0.f,0.f};
            #pragma unroll
            for (int k2 = 0; k2 < 32; k2++) {
                float4 u = red2[k2][t];
                s.x += u.x; s.y += u.y; s.z += u.z; s.w += u.w;
            }
            const float sc = 1.0f / Nv;
            s.x *= sc; s.y *= sc; s.z *= sc; s.w *= sc;
            ((float4*)g_cs)[(b * Nv + i) * 8 + t] = s;
        }
        __syncthreads();
    }
    if (t < 8) {
        #pragma unroll
        for (int r = 0; r < 4; r++) {
            int i = i0 + r;
            ((float4*)g_dgx)[(b * Nv + i) * 8 + t] = xb4[((size_t)i * Nv + i) * 8 + t];
        }
    }
    // rw partials: contract acc8 with w1 rows (c = c4*4..+3), reduce over c4
    #pragma unroll
    for (int k = 0; k < 8; k++) {
        int j = jb + 32 * k;
        #pragma unroll
        for (int m = 0; m < 4; m++) {
            float wc = acc8[k].x * w1[(c4 * 4 + 0) * Mv + m]
                     + acc8[k].y * w1[(c4 * 4 + 1) * Mv + m]
                     + acc8[k].z * w1[(c4 * 4 + 2) * Mv + m]
                     + acc8[k].w * w1[(c4 * 4 + 3) * Mv + m];
            redw[j][c4 * 4 + m] = wc;
        }
    }
    __syncthreads();
    {
        float4 rw;
        #pragma unroll
        for (int m = 0; m < 4; m++) {
            float s = 0.f;
            #pragma unroll
            for (int q = 0; q < 8; q++) s += redw[t][q * 4 + m];
            ((float*)&rw)[m] = s;
        }
        ((float4*)g_rwP)[((size_t)b * 64 + bx) * Nv + t] = rw;
    }
}

// ---------------- K2: neighborhood linear + sigmoid ---------------------------
// rowcolsum from cs (== rs total); rs@w1 term from resolved rwP partials.
__global__ void k_neighb(const float* __restrict__ w1, const float* __restrict__ b1,
                         const float* __restrict__ w0, const float* __restrict__ b0) {
    int b = blockIdx.x, t = threadIdx.x;
    int c = t & 31, sub = t >> 5;
    float ar = 0.f, ad = 0.f;
    for (int n = sub; n < Nv; n += 8) {
        ar += g_cs[(b * Nv + n) * Cv + c];
        ad += g_dgx[(b * Nv + n) * Cv + c];
    }
    __shared__ float red[8][64];
    __shared__ float obj0[64];
    __shared__ float redm[64][4];
    __shared__ float t0nb[4];
    red[sub][c] = ar;
    red[sub][32 + c] = ad;
    __syncthreads();
    if (t < 64) {
        float s = 0.f;
        #pragma unroll
        for (int k = 0; k < 8; k++) s += red[k][t];
        obj0[t] = s * (1.0f / Nv);
    }
    __syncthreads();
    {   // parallel matvec obj0[64] @ w0[64x4]
        int k = t >> 2, m = t & 3;
        redm[k][m] = obj0[k] * w0[k * Mv + m];
    }
    __syncthreads();
    if (t < 4) {
        float v = b0[t];
        #pragma unroll
        for (int k = 0; k < 64; k++) v += redm[k][t];
        t0nb[t] = v;
    }
    __syncthreads();
    int n = t;
    float4 rwv = {0.f,0.f,0.f,0.f};
    for (int g = 0; g < 64; g++) {
        float4 p = ((const float4*)g_rwP)[((size_t)b * 64 + g) * Nv + n];
        rwv.x += p.x; rwv.y += p.y; rwv.z += p.z; rwv.w += p.w;
    }
    float node[4];
    #pragma unroll
    for (int m = 0; m < 4; m++)
        node[m] = t0nb[m] + b1[m] + ((float*)&rwv)[m] * (1.0f / Nv);
    for (int cc = 0; cc < Cv; cc++) {
        float s = g_cs[(b * Nv + n) * Cv + cc];
        float d = g_dgx[(b * Nv + n) * Cv + cc];
        #pragma unroll
        for (int m = 0; m < 4; m++)
            node[m] += s * w1[(Cv + cc) * Mv + m] + d * w1[(2 * Cv + cc) * Mv + m];
    }
    #pragma unroll
    for (int m = 0; m < 4; m++)
        g_nb[(b * Nv + n) * Mv + m] = 1.0f / (1.0f + expf(-node[m]));
}

// ---------------- K3: fused wsum(both dirs, wave-split) + add -----------------
// waves 0-1: S1 via column gather; waves 2-3: S2 via row n. Replica atomics,
// then the add epilogue inline -> g_addv (without the w0d/t0 term).
__global__ __launch_bounds__(256) void k_fused(const float* __restrict__ x,
    const float* __restrict__ w1d, const float* __restrict__ b1d,
    const float* __restrict__ b2d, const float* __restrict__ b0d) {
    int n = blockIdx.x, b = blockIdx.y;
    int t = threadIdx.x;

    __shared__ __align__(16) float4 nb4[Nv];
    __shared__ float red[2][16][132];
    __shared__ float S1l[MCv], S2l[MCv];
    __shared__ float redD[4][64];

    nb4[t] = ((const float4*)g_nb)[b * Nv + t];
    __syncthreads();

    const float4* xb4 = (const float4*)(x + (size_t)b * Nv * Nv * Cv);
    int half = t >> 7, tt = t & 127, c4 = tt & 7, sub = tt >> 3;   // 16 subs x 8 c4
    float4 a[4];
    #pragma unroll
    for (int m = 0; m < 4; m++) a[m] = {0.f,0.f,0.f,0.f};
    for (int i = sub; i < Nv; i += 16) {
        float4 v = half ? xb4[((size_t)n * Nv + i) * 8 + c4]    // S2: row n
                        : xb4[((size_t)i * Nv + n) * 8 + c4];   // S1: column n (gather)
        float4 nv = nb4[i];
        a[0].x += nv.x*v.x; a[0].y += nv.x*v.y; a[0].z += nv.x*v.z; a[0].w += nv.x*v.w;
        a[1].x += nv.y*v.x; a[1].y += nv.y*v.y; a[1].z += nv.y*v.z; a[1].w += nv.y*v.w;
        a[2].x += nv.z*v.x; a[2].y += nv.z*v.y; a[2].z += nv.z*v.z; a[2].w += nv.z*v.w;
        a[3].x += nv.w*v.x; a[3].y += nv.w*v.y; a[3].z += nv.w*v.z; a[3].w += nv.w*v.w;
    }
    #pragma unroll
    for (int m = 0; m < 4; m++) {
        red[half][sub][m*32 + c4*4+0] = a[m].x; red[half][sub][m*32 + c4*4+1] = a[m].y;
        red[half][sub][m*32 + c4*4+2] = a[m].z; red[half][sub][m*32 + c4*4+3] = a[m].w;
    }
    __syncthreads();
    if (t < 128) {
        float s = 0.f;
        #pragma unroll
        for (int k = 0; k < 16; k++) s += red[0][k][t];
        S1l[t] = s;
        int m = t >> 5, c = t & 31;
        float nv = ((const float*)&nb4[n])[m];
        int rep = ((n & 7) * Bv + b) * MCv + t;
        atomicAdd(&g_rcs2R[rep], nv * s);
        atomicAdd(&g_ds2R [rep], nv * nv * g_dgx[(b * Nv + n) * Cv + c]);
    } else {
        int u = t - 128;
        float s = 0.f;
        #pragma unroll
        for (int k = 0; k < 16; k++) s += red[1][k][u];
        S2l[u] = s;
    }
    __syncthreads();

    // ---- add epilogue (no w0d/t0 term; that is resolved in k_main) ----
    {
        int o = t & 63, ks = t >> 6;
        const float invN = 1.0f / Nv;
        float nv = ((const float*)&nb4[n])[ks];
        float f = nv * invN, d2 = nv * nv;
        const float* dgr = g_dgx + (size_t)(b * Nv + n) * Cv;
        float acc = 0.f;
        #pragma unroll 8
        for (int cc = 0; cc < 32; cc++) {
            int mc = ks * 32 + cc;
            acc += f * S1l[mc] * w1d[(size_t)mc * OUTv + o]
                 + f * S2l[mc] * w1d[(size_t)(MCv + mc) * OUTv + o]
                 + d2 * dgr[cc] * w1d[(size_t)(2 * MCv + mc) * OUTv + o];
        }
        redD[ks][o] = acc;
    }
    __syncthreads();
    if (t < 64) {
        float v = redD[0][t] + redD[1][t] + redD[2][t] + redD[3][t]
                + b1d[t] + b2d[t] + b0d[t];
        g_addv[(size_t)(b * Nv + n) * OUTv + t] = v;
    }
}

// ---------------- K4: main term via MFMA f16, 2 output rows per block ---------
// Resolves t0 (w0d term) per block from the replicas (complete at kernel bound).
#define XPAD 40
__global__ __launch_bounds__(256) void k_main(const float* __restrict__ x,
                                              float* __restrict__ out,
                                              const float* __restrict__ w0d) {
    int jt = blockIdx.x, ip = blockIdx.y, b = blockIdx.z;
    int i0 = ip * 2, i1 = i0 + 1;
    int j0 = jt * 128;
    int t = threadIdx.x;
    int lane = t & 63, w = t >> 6;
    int rowA = lane & 15, quad = lane >> 4;

    __shared__ __align__(16) _Float16 Wl[8 * 4 * 64 * 8];   // 32 KB
    __shared__ __align__(16) _Float16 Xt0[128 * XPAD];      // 10 KB each
    __shared__ __align__(16) _Float16 Xb0[128 * XPAD];
    __shared__ __align__(16) _Float16 Xt1[128 * XPAD];
    __shared__ __align__(16) _Float16 Xb1[128 * XPAD];
    __shared__ float rcl[MCv], dsl[MCv];
    __shared__ float t0red[4][64];
    __shared__ float t0l[64];

    {
        const float4* src = (const float4*)g_wfrag;
        float4* dst = (float4*)Wl;
        #pragma unroll
        for (int r = 0; r < 8; r++) dst[r * 256 + t] = src[r * 256 + t];
    }
    {
        const float4* x4 = (const float4*)x;
        #pragma unroll
        for (int r = 0; r < 4; r++) {
            int idx = r * 256 + t;
            int j = idx >> 3, c4 = idx & 7;
            float4 v0 = x4[((size_t)(b * Nv + i0) * Nv + j0 + j) * 8 + c4];
            float4 v1 = x4[((size_t)(b * Nv + i1) * Nv + j0 + j) * 8 + c4];
            float4 u0 = x4[((size_t)(b * Nv + j0 + j) * Nv + i0) * 8 + c4];
            float4 u1 = x4[((size_t)(b * Nv + j0 + j) * Nv + i1) * 8 + c4];
            h4 h0; h0[0] = (_Float16)v0.x; h0[1] = (_Float16)v0.y;
            h0[2] = (_Float16)v0.z; h0[3] = (_Float16)v0.w;
            *(h4*)&Xt0[j * XPAD + c4 * 4] = h0;
            h4 h1; h1[0] = (_Float16)v1.x; h1[1] = (_Float16)v1.y;
            h1[2] = (_Float16)v1.z; h1[3] = (_Float16)v1.w;
            *(h4*)&Xt1[j * XPAD + c4 * 4] = h1;
            h4 g0; g0[0] = (_Float16)u0.x; g0[1] = (_Float16)u0.y;
            g0[2] = (_Float16)u0.z; g0[3] = (_Float16)u0.w;
            *(h4*)&Xb0[j * XPAD + c4 * 4] = g0;
            h4 g1; g1[0] = (_Float16)u1.x; g1[1] = (_Float16)u1.y;
            g1[2] = (_Float16)u1.z; g1[3] = (_Float16)u1.w;
            *(h4*)&Xb1[j * XPAD + c4 * 4] = g1;
        }
    }
    if (t < 128) {
        float s = 0.f;
        #pragma unroll
        for (int r = 0; r < 8; r++) s += g_rcs2R[(r * Bv + b) * MCv + t];
        rcl[t] = s;
    } else {
        int tt = t - 128;
        float s = 0.f;
        #pragma unroll
        for (int r = 0; r < 8; r++) s += g_ds2R[(r * Bv + b) * MCv + tt];
        dsl[tt] = s;
    }
    int jl1 = w * 32 + rowA, jl2 = jl1 + 16;
    _Float16 e1h0[4], e2h0[4], e1h1[4], e2h1[4];
    {
        const float* ni0 = g_nb + (size_t)(b * Nv + i0) * Mv;
        const float* ni1 = g_nb + (size_t)(b * Nv + i1) * Mv;
        const float* n1 = g_nb + (size_t)(b * Nv + j0 + jl1) * Mv;
        const float* n2 = g_nb + (size_t)(b * Nv + j0 + jl2) * Mv;
        #pragma unroll
        for (int m = 0; m < 4; m++) {
            e1h0[m] = (_Float16)(ni0[m] * n1[m]);
            e2h0[m] = (_Float16)(ni0[m] * n2[m]);
            e1h1[m] = (_Float16)(ni1[m] * n1[m]);
            e2h1[m] = (_Float16)(ni1[m] * n2[m]);
        }
    }
    __syncthreads();
    {
        int o = t & 63, ks = t >> 6;
        const float invN = 1.0f / Nv;
        const float invN2 = invN * invN;
        float a0 = 0.f;
        #pragma unroll 8
        for (int cc = 0; cc < 32; cc++) {
            int mc = ks * 32 + cc;
            a0 += invN2 * rcl[mc] * w0d[(size_t)mc * OUTv + o]
                + invN  * dsl[mc] * w0d[(size_t)(MCv + mc) * OUTv + o];
        }
        t0red[ks][o] = a0;
    }
    __syncthreads();
    if (t < 64) t0l[t] = t0red[0][t] + t0red[1][t] + t0red[2][t] + t0red[3][t];
    __syncthreads();

    f4 acc[2][2][4];   // [i][js][q]
    #pragma unroll
    for (int ii = 0; ii < 2; ii++)
        #pragma unroll
        for (int js = 0; js < 2; js++)
            #pragma unroll
            for (int q = 0; q < 4; q++) acc[ii][js][q] = {0.f, 0.f, 0.f, 0.f};

    const h8* Wf = (const h8*)Wl;
    #pragma unroll
    for (int part = 0; part < 2; part++) {
        const _Float16* X0 = part ? Xb0 : Xt0;
        const _Float16* X1 = part ? Xb1 : Xt1;
        h8 xv1_0 = *(const h8*)&X0[jl1 * XPAD + quad * 8];
        h8 xv2_0 = *(const h8*)&X0[jl2 * XPAD + quad * 8];
        h8 xv1_1 = *(const h8*)&X1[jl1 * XPAD + quad * 8];
        h8 xv2_1 = *(const h8*)&X1[jl2 * XPAD + quad * 8];
        #pragma unroll
        for (int m = 0; m < 4; m++) {
            h8 a1_0 = xv1_0 * e1h0[m];
            h8 a2_0 = xv2_0 * e2h0[m];
            h8 a1_1 = xv1_1 * e1h1[m];
            h8 a2_1 = xv2_1 * e2h1[m];
            int s = part * 4 + m;
            #pragma unroll
            for (int q = 0; q < 4; q++) {
                h8 bf = Wf[(s * 4 + q) * 64 + lane];
                acc[0][0][q] = __builtin_amdgcn_mfma_f32_16x16x32_f16(a1_0, bf, acc[0][0][q], 0, 0, 0);
                acc[0][1][q] = __builtin_amdgcn_mfma_f32_16x16x32_f16(a2_0, bf, acc[0][1][q], 0, 0, 0);
                acc[1][0][q] = __builtin_amdgcn_mfma_f32_16x16x32_f16(a1_1, bf, acc[1][0][q], 0, 0, 0);
                acc[1][1][q] = __builtin_amdgcn_mfma_f32_16x16x32_f16(a2_1, bf, acc[1][1][q], 0, 0, 0);
            }
        }
    }
    #pragma unroll
    for (int js = 0; js < 2; js++) {
        int jbase = j0 + w * 32 + js * 16 + quad * 4;
        #pragma unroll
        for (int q = 0; q < 4; q++) {
            int o = q * 16 + rowA;
            float tv = t0l[o];
            #pragma unroll
            for (int r = 0; r < 4; r++) {
                int j = jbase + r;
                float av = g_addv[(size_t)(b * Nv + j) * OUTv + o] + tv;
                out[(((size_t)(b * Nv + i0)) * Nv + j) * OUTv + o] = acc[0][js][q][r] + av;
                out[(((size_t)(b * Nv + i1)) * Nv + j) * OUTv + o] = acc[1][js][q][r] + av;
            }
        }
    }
}

extern "C" void kernel_launch(void* const* d_in, const int* in_sizes, int n_in,
                              void* d_out, int out_size, void* d_ws, size_t ws_size,
                              hipStream_t stream) {
    const float* x     = (const float*)d_in[0];
    const float* w1_nb = (const float*)d_in[1];
    const float* b1_nb = (const float*)d_in[2];
    const float* w0_nb = (const float*)d_in[3];
    const float* b0_nb = (const float*)d_in[4];
    const float* w2d   = (const float*)d_in[5];
    const float* b2d   = (const float*)d_in[6];
    const float* w1d   = (const float*)d_in[7];
    const float* b1d   = (const float*)d_in[8];
    const float* w0d   = (const float*)d_in[9];
    const float* b0d   = (const float*)d_in[10];
    float* out = (float*)d_out;
    (void)d_ws; (void)ws_size;

    hipLaunchKernelGGL(k_contract1, dim3(64 + 9, Bv), dim3(256), 0, stream,
                       x, w2d, w1_nb);
    hipLaunchKernelGGL(k_neighb, dim3(Bv), dim3(256), 0, stream,
                       w1_nb, b1_nb, w0_nb, b0_nb);
    hipLaunchKernelGGL(k_fused, dim3(Nv, Bv), dim3(256), 0, stream,
                       x, w1d, b1d, b2d, b0d);
    hipLaunchKernelGGL(k_main, dim3(2, Nv / 2, Bv), dim3(256), 0, stream, x, out, w0d);
}

// Round 10
// 167.292 us; speedup vs baseline: 1.0090x; 1.0090x over previous
//
#include <hip/hip_runtime.h>
#include <math.h>

#define Bv 4
#define Nv 256
#define Cv 32
#define Mv 4
#define OUTv 64
#define MCv (Mv*Cv)      // 128

typedef _Float16 h8 __attribute__((ext_vector_type(8)));
typedef _Float16 h4 __attribute__((ext_vector_type(4)));
typedef float f4 __attribute__((ext_vector_type(4)));

// ---- static device scratch ----
__device__ __align__(16) float g_rs  [Bv * Nv * Cv];
__device__ __align__(16) float g_cs  [Bv * Nv * Cv];
__device__ __align__(16) float g_dgx [Bv * Nv * Cv];
__device__ __align__(16) float g_nb  [Bv * Nv * Mv];
__device__ __align__(16) float g_rcs2R[8 * Bv * MCv];   // 8 XCD-aligned atomic replicas
__device__ __align__(16) float g_ds2R [8 * Bv * MCv];   // 8 XCD-aligned atomic replicas
__device__ __align__(16) float g_addv[Bv * Nv * OUTv];  // addv WITHOUT the w0d (t0) term
__device__ __align__(16) _Float16 g_wfrag[8 * 4 * 64 * 8];   // 32 KB

// ---------------- K1: row/col/diag contractions, direction-split --------------
// (R8 best-measured form.) Absorbs w2d pack + replica zeroing.
__global__ __launch_bounds__(256) void k_contract1(const float* __restrict__ x,
                                                   const float* __restrict__ w2d) {
    int bx = blockIdx.x, b = blockIdx.y;
    int t = threadIdx.x;
    if (bx >= 2 * Nv) {
        if (b != 0) return;
        int r = bx - 2 * Nv;
        if (r == 8) {                    // zero rcs2/ds2 replicas (2 x 4096 floats)
            float4 z = {0.f,0.f,0.f,0.f};
            #pragma unroll
            for (int k = 0; k < 4; k++) {
                ((float4*)g_rcs2R)[k * 256 + t] = z;
                ((float4*)g_ds2R )[k * 256 + t] = z;
            }
            return;
        }
        int fi = r * 256 + t;
        int s = fi >> 8, q = (fi >> 6) & 3, lane = fi & 63;
        int k0 = s * 32 + ((lane >> 4) << 3);
        int o = q * 16 + (lane & 15);
        #pragma unroll
        for (int jj = 0; jj < 8; jj++)
            g_wfrag[fi * 8 + jj] = (_Float16)w2d[(size_t)(k0 + jj) * OUTv + o];
        return;
    }
    int c4 = t & 7, sub = t >> 3;   // 32 subs x 8 float4-cols
    const float4* xb4 = (const float4*)(x + (size_t)b * Nv * Nv * Cv);
    __shared__ float red[32][36];
    float4 acc = {0.f,0.f,0.f,0.f};
    if (bx < Nv) {
        int n = bx;
        for (int i = sub; i < Nv; i += 32) {
            float4 v = xb4[((size_t)i * Nv + n) * 8 + c4];
            acc.x += v.x; acc.y += v.y; acc.z += v.z; acc.w += v.w;
        }
        red[sub][c4*4+0] = acc.x; red[sub][c4*4+1] = acc.y;
        red[sub][c4*4+2] = acc.z; red[sub][c4*4+3] = acc.w;
        __syncthreads();
        if (t < 32) {
            float s = 0.f;
            #pragma unroll
            for (int k = 0; k < 32; k++) s += red[k][t];
            g_rs[(b * Nv + n) * Cv + t] = s * (1.0f / Nv);
        }
        if (t < 8) ((float4*)g_dgx)[(b * Nv + n) * 8 + t] = xb4[((size_t)n * Nv + n) * 8 + t];
    } else {
        int n = bx - Nv;
        for (int j = sub; j < Nv; j += 32) {
            float4 v = xb4[((size_t)n * Nv + j) * 8 + c4];
            acc.x += v.x; acc.y += v.y; acc.z += v.z; acc.w += v.w;
        }
        red[sub][c4*4+0] = acc.x; red[sub][c4*4+1] = acc.y;
        red[sub][c4*4+2] = acc.z; red[sub][c4*4+3] = acc.w;
        __syncthreads();
        if (t < 32) {
            float s = 0.f;
            #pragma unroll
            for (int k = 0; k < 32; k++) s += red[k][t];
            g_cs[(b * Nv + n) * Cv + t] = s * (1.0f / Nv);
        }
    }
}

// ---------------- K2: neighborhood linear + sigmoid (parallel matvec) ---------
__global__ void k_neighb(const float* __restrict__ w1, const float* __restrict__ b1,
                         const float* __restrict__ w0, const float* __restrict__ b0) {
    int b = blockIdx.x, t = threadIdx.x;
    int c = t & 31, sub = t >> 5;
    float ar = 0.f, ad = 0.f;
    for (int n = sub; n < Nv; n += 8) {
        ar += g_rs[(b * Nv + n) * Cv + c];
        ad += g_dgx[(b * Nv + n) * Cv + c];
    }
    __shared__ float red[8][64];
    __shared__ float obj0[64];
    __shared__ float redm[64][4];
    __shared__ float t0nb[4];
    red[sub][c] = ar;
    red[sub][32 + c] = ad;
    __syncthreads();
    if (t < 64) {
        float s = 0.f;
        #pragma unroll
        for (int k = 0; k < 8; k++) s += red[k][t];
        obj0[t] = s * (1.0f / Nv);
    }
    __syncthreads();
    {   // parallel matvec obj0[64] @ w0[64x4]
        int k = t >> 2, m = t & 3;
        redm[k][m] = obj0[k] * w0[k * Mv + m];
    }
    __syncthreads();
    if (t < 4) {
        float v = b0[t];
        #pragma unroll
        for (int k = 0; k < 64; k++) v += redm[k][t];
        t0nb[t] = v;
    }
    __syncthreads();
    int n = t;
    float node[4];
    #pragma unroll
    for (int m = 0; m < 4; m++) node[m] = t0nb[m] + b1[m];
    for (int cc = 0; cc < Cv; cc++) {
        float r = g_rs[(b * Nv + n) * Cv + cc];
        float s = g_cs[(b * Nv + n) * Cv + cc];
        float d = g_dgx[(b * Nv + n) * Cv + cc];
        #pragma unroll
        for (int m = 0; m < 4; m++)
            node[m] += r * w1[cc * Mv + m] + s * w1[(Cv + cc) * Mv + m] + d * w1[(2 * Cv + cc) * Mv + m];
    }
    #pragma unroll
    for (int m = 0; m < 4; m++)
        g_nb[(b * Nv + n) * Mv + m] = 1.0f / (1.0f + expf(-node[m]));
}

// ---------------- K3: fused wsum + add, 512 threads (halved critical chain) ---
// wave-groups 0-3: S1 column gather (32 subs, 8 i-iters); 4-7: S2 row (same).
// Reduce split over 256 threads; epilogue c-loop split over 8 wave-slots.
__global__ __launch_bounds__(512) void k_fused(const float* __restrict__ x,
    const float* __restrict__ w1d, const float* __restrict__ b1d,
    const float* __restrict__ b2d, const float* __restrict__ b0d) {
    int n = blockIdx.x, b = blockIdx.y;
    int t = threadIdx.x;

    __shared__ __align__(16) float4 nb4[Nv];
    __shared__ float red[2][32][132];              // 33 KB; redD aliased on top
    __shared__ float S1l[MCv], S2l[MCv];
    float (*redD)[64] = (float(*)[64])&red[0][0][0];

    if (t < Nv) nb4[t] = ((const float4*)g_nb)[b * Nv + t];
    __syncthreads();

    const float4* xb4 = (const float4*)(x + (size_t)b * Nv * Nv * Cv);
    int dir = t >> 8, tt = t & 255, c4 = tt & 7, sub = tt >> 3;   // 32 subs x 8 c4
    float4 a[4];
    #pragma unroll
    for (int m = 0; m < 4; m++) a[m] = {0.f,0.f,0.f,0.f};
    for (int i = sub; i < Nv; i += 32) {
        float4 v = dir ? xb4[((size_t)n * Nv + i) * 8 + c4]    // S2: row n
                       : xb4[((size_t)i * Nv + n) * 8 + c4];   // S1: column n (gather)
        float4 nv = nb4[i];
        a[0].x += nv.x*v.x; a[0].y += nv.x*v.y; a[0].z += nv.x*v.z; a[0].w += nv.x*v.w;
        a[1].x += nv.y*v.x; a[1].y += nv.y*v.y; a[1].z += nv.y*v.z; a[1].w += nv.y*v.w;
        a[2].x += nv.z*v.x; a[2].y += nv.z*v.y; a[2].z += nv.z*v.z; a[2].w += nv.z*v.w;
        a[3].x += nv.w*v.x; a[3].y += nv.w*v.y; a[3].z += nv.w*v.z; a[3].w += nv.w*v.w;
    }
    #pragma unroll
    for (int m = 0; m < 4; m++) {
        red[dir][sub][m*32 + c4*4+0] = a[m].x; red[dir][sub][m*32 + c4*4+1] = a[m].y;
        red[dir][sub][m*32 + c4*4+2] = a[m].z; red[dir][sub][m*32 + c4*4+3] = a[m].w;
    }
    __syncthreads();
    if (t < 256) {
        int which = t >> 7, u = t & 127;
        float s = 0.f;
        #pragma unroll
        for (int k = 0; k < 32; k++) s += red[which][k][u];
        if (which == 0) {
            S1l[u] = s;
            int m = u >> 5, c = u & 31;
            float nv = ((const float*)&nb4[n])[m];
            int rep = ((n & 7) * Bv + b) * MCv + u;
            atomicAdd(&g_rcs2R[rep], nv * s);
            atomicAdd(&g_ds2R [rep], nv * nv * g_dgx[(b * Nv + n) * Cv + c]);
        } else {
            S2l[u] = s;
        }
    }
    __syncthreads();

    // ---- add epilogue, split over 8 wave-slots x 16 c each ----
    {
        int o = t & 63, k8 = t >> 6;   // k8 = 0..7
        const float invN = 1.0f / Nv;
        float nv = ((const float*)&nb4[n])[k8 >> 1];
        float f = nv * invN, d2 = nv * nv;
        const float* dgr = g_dgx + (size_t)(b * Nv + n) * Cv;
        float acc = 0.f;
        #pragma unroll 8
        for (int cc = 0; cc < 16; cc++) {
            int mc = k8 * 16 + cc;
            acc += f * S1l[mc] * w1d[(size_t)mc * OUTv + o]
                 + f * S2l[mc] * w1d[(size_t)(MCv + mc) * OUTv + o]
                 + d2 * dgr[mc & 31] * w1d[(size_t)(2 * MCv + mc) * OUTv + o];
        }
        redD[k8][o] = acc;
    }
    __syncthreads();
    if (t < 64) {
        float v = redD[0][t] + redD[1][t] + redD[2][t] + redD[3][t]
                + redD[4][t] + redD[5][t] + redD[6][t] + redD[7][t]
                + b1d[t] + b2d[t] + b0d[t];
        g_addv[(size_t)(b * Nv + n) * OUTv + t] = v;
    }
}

// ---------------- K4: main term via MFMA f16, 2 output rows per block ---------
// Resolves t0 (w0d term) per block from the replicas (complete at kernel bound).
#define XPAD 40
__global__ __launch_bounds__(256) void k_main(const float* __restrict__ x,
                                              float* __restrict__ out,
                                              const float* __restrict__ w0d) {
    int jt = blockIdx.x, ip = blockIdx.y, b = blockIdx.z;
    int i0 = ip * 2, i1 = i0 + 1;
    int j0 = jt * 128;
    int t = threadIdx.x;
    int lane = t & 63, w = t >> 6;
    int rowA = lane & 15, quad = lane >> 4;

    __shared__ __align__(16) _Float16 Wl[8 * 4 * 64 * 8];   // 32 KB
    __shared__ __align__(16) _Float16 Xt0[128 * XPAD];      // 10 KB each
    __shared__ __align__(16) _Float16 Xb0[128 * XPAD];
    __shared__ __align__(16) _Float16 Xt1[128 * XPAD];
    __shared__ __align__(16) _Float16 Xb1[128 * XPAD];
    __shared__ float rcl[MCv], dsl[MCv];
    __shared__ float t0red[4][64];
    __shared__ float t0l[64];

    {
        const float4* src = (const float4*)g_wfrag;
        float4* dst = (float4*)Wl;
        #pragma unroll
        for (int r = 0; r < 8; r++) dst[r * 256 + t] = src[r * 256 + t];
    }
    {
        const float4* x4 = (const float4*)x;
        #pragma unroll
        for (int r = 0; r < 4; r++) {
            int idx = r * 256 + t;
            int j = idx >> 3, c4 = idx & 7;
            float4 v0 = x4[((size_t)(b * Nv + i0) * Nv + j0 + j) * 8 + c4];
            float4 v1 = x4[((size_t)(b * Nv + i1) * Nv + j0 + j) * 8 + c4];
            float4 u0 = x4[((size_t)(b * Nv + j0 + j) * Nv + i0) * 8 + c4];
            float4 u1 = x4[((size_t)(b * Nv + j0 + j) * Nv + i1) * 8 + c4];
            h4 h0; h0[0] = (_Float16)v0.x; h0[1] = (_Float16)v0.y;
            h0[2] = (_Float16)v0.z; h0[3] = (_Float16)v0.w;
            *(h4*)&Xt0[j * XPAD + c4 * 4] = h0;
            h4 h1; h1[0] = (_Float16)v1.x; h1[1] = (_Float16)v1.y;
            h1[2] = (_Float16)v1.z; h1[3] = (_Float16)v1.w;
            *(h4*)&Xt1[j * XPAD + c4 * 4] = h1;
            h4 g0; g0[0] = (_Float16)u0.x; g0[1] = (_Float16)u0.y;
            g0[2] = (_Float16)u0.z; g0[3] = (_Float16)u0.w;
            *(h4*)&Xb0[j * XPAD + c4 * 4] = g0;
            h4 g1; g1[0] = (_Float16)u1.x; g1[1] = (_Float16)u1.y;
            g1[2] = (_Float16)u1.z; g1[3] = (_Float16)u1.w;
            *(h4*)&Xb1[j * XPAD + c4 * 4] = g1;
        }
    }
    if (t < 128) {
        float s = 0.f;
        #pragma unroll
        for (int r = 0; r < 8; r++) s += g_rcs2R[(r * Bv + b) * MCv + t];
        rcl[t] = s;
    } else {
        int tt = t - 128;
        float s = 0.f;
        #pragma unroll
        for (int r = 0; r < 8; r++) s += g_ds2R[(r * Bv + b) * MCv + tt];
        dsl[tt] = s;
    }
    int jl1 = w * 32 + rowA, jl2 = jl1 + 16;
    _Float16 e1h0[4], e2h0[4], e1h1[4], e2h1[4];
    {
        const float* ni0 = g_nb + (size_t)(b * Nv + i0) * Mv;
        const float* ni1 = g_nb + (size_t)(b * Nv + i1) * Mv;
        const float* n1 = g_nb + (size_t)(b * Nv + j0 + jl1) * Mv;
        const float* n2 = g_nb + (size_t)(b * Nv + j0 + jl2) * Mv;
        #pragma unroll
        for (int m = 0; m < 4; m++) {
            e1h0[m] = (_Float16)(ni0[m] * n1[m]);
            e2h0[m] = (_Float16)(ni0[m] * n2[m]);
            e1h1[m] = (_Float16)(ni1[m] * n1[m]);
            e2h1[m] = (_Float16)(ni1[m] * n2[m]);
        }
    }
    __syncthreads();
    {
        int o = t & 63, ks = t >> 6;
        const float invN = 1.0f / Nv;
        const float invN2 = invN * invN;
        float a0 = 0.f;
        #pragma unroll 8
        for (int cc = 0; cc < 32; cc++) {
            int mc = ks * 32 + cc;
            a0 += invN2 * rcl[mc] * w0d[(size_t)mc * OUTv + o]
                + invN  * dsl[mc] * w0d[(size_t)(MCv + mc) * OUTv + o];
        }
        t0red[ks][o] = a0;
    }
    __syncthreads();
    if (t < 64) t0l[t] = t0red[0][t] + t0red[1][t] + t0red[2][t] + t0red[3][t];
    __syncthreads();

    f4 acc[2][2][4];   // [i][js][q]
    #pragma unroll
    for (int ii = 0; ii < 2; ii++)
        #pragma unroll
        for (int js = 0; js < 2; js++)
            #pragma unroll
            for (int q = 0; q < 4; q++) acc[ii][js][q] = {0.f, 0.f, 0.f, 0.f};

    const h8* Wf = (const h8*)Wl;
    #pragma unroll
    for (int part = 0; part < 2; part++) {
        const _Float16* X0 = part ? Xb0 : Xt0;
        const _Float16* X1 = part ? Xb1 : Xt1;
        h8 xv1_0 = *(const h8*)&X0[jl1 * XPAD + quad * 8];
        h8 xv2_0 = *(const h8*)&X0[jl2 * XPAD + quad * 8];
        h8 xv1_1 = *(const h8*)&X1[jl1 * XPAD + quad * 8];
        h8 xv2_1 = *(const h8*)&X1[jl2 * XPAD + quad * 8];
        #pragma unroll
        for (int m = 0; m < 4; m++) {
            h8 a1_0 = xv1_0 * e1h0[m];
            h8 a2_0 = xv2_0 * e2h0[m];
            h8 a1_1 = xv1_1 * e1h1[m];
            h8 a2_1 = xv2_1 * e2h1[m];
            int s = part * 4 + m;
            #pragma unroll
            for (int q = 0; q < 4; q++) {
                h8 bf = Wf[(s * 4 + q) * 64 + lane];
                acc[0][0][q] = __builtin_amdgcn_mfma_f32_16x16x32_f16(a1_0, bf, acc[0][0][q], 0, 0, 0);
                acc[0][1][q] = __builtin_amdgcn_mfma_f32_16x16x32_f16(a2_0, bf, acc[0][1][q], 0, 0, 0);
                acc[1][0][q] = __builtin_amdgcn_mfma_f32_16x16x32_f16(a1_1, bf, acc[1][0][q], 0, 0, 0);
                acc[1][1][q] = __builtin_amdgcn_mfma_f32_16x16x32_f16(a2_1, bf, acc[1][1][q], 0, 0, 0);
            }
        }
    }
    #pragma unroll
    for (int js = 0; js < 2; js++) {
        int jbase = j0 + w * 32 + js * 16 + quad * 4;
        #pragma unroll
        for (int q = 0; q < 4; q++) {
            int o = q * 16 + rowA;
            float tv = t0l[o];
            #pragma unroll
            for (int r = 0; r < 4; r++) {
                int j = jbase + r;
                float av = g_addv[(size_t)(b * Nv + j) * OUTv + o] + tv;
                out[(((size_t)(b * Nv + i0)) * Nv + j) * OUTv + o] = acc[0][js][q][r] + av;
                out[(((size_t)(b * Nv + i1)) * Nv + j) * OUTv + o] = acc[1][js][q][r] + av;
            }
        }
    }
}

extern "C" void kernel_launch(void* const* d_in, const int* in_sizes, int n_in,
                              void* d_out, int out_size, void* d_ws, size_t ws_size,
                              hipStream_t stream) {
    const float* x     = (const float*)d_in[0];
    const float* w1_nb = (const float*)d_in[1];
    const float* b1_nb = (const float*)d_in[2];
    const float* w0_nb = (const float*)d_in[3];
    const float* b0_nb = (const float*)d_in[4];
    const float* w2d   = (const float*)d_in[5];
    const float* b2d   = (const float*)d_in[6];
    const float* w1d   = (const float*)d_in[7];
    const float* b1d   = (const float*)d_in[8];
    const float* w0d   = (const float*)d_in[9];
    const float* b0d   = (const float*)d_in[10];
    float* out = (float*)d_out;
    (void)d_ws; (void)ws_size;

    hipLaunchKernelGGL(k_contract1, dim3(2 * Nv + 9, Bv), dim3(256), 0, stream, x, w2d);
    hipLaunchKernelGGL(k_neighb, dim3(Bv), dim3(256), 0, stream,
                       w1_nb, b1_nb, w0_nb, b0_nb);
    hipLaunchKernelGGL(k_fused, dim3(Nv, Bv), dim3(512), 0, stream,
                       x, w1d, b1d, b2d, b0d);
    hipLaunchKernelGGL(k_main, dim3(2, Nv / 2, Bv), dim3(256), 0, stream, x, out, w0d);
}